// Round 12
// baseline (380.441 us; speedup 1.0000x reference)
//
#include <hip/hip_runtime.h>
#include <cstdint>

typedef unsigned short u16;
typedef __attribute__((ext_vector_type(8))) short short8;
typedef __attribute__((ext_vector_type(4))) short short4v;
typedef __attribute__((ext_vector_type(4))) float f32x4;
typedef __attribute__((ext_vector_type(4))) unsigned short u16x4;
typedef __attribute__((ext_vector_type(2))) float f32x2;
typedef __attribute__((ext_vector_type(2))) __bf16 bf16x2;

// B=4 R=64 C=64 D=512 H=4 DH=128 S=4096, M = B*S = 16384

#if defined(__has_builtin)
#if __has_builtin(__builtin_amdgcn_mfma_f32_16x16x16bf16_1k)
#define HAVE_MFMA16 1
#endif
#endif

// HW packed f32->bf16 (RNE): single v_cvt_pk_bf16_f32.
__device__ __forceinline__ uint32_t pk2(float a, float b) {
  f32x2 t;
  t[0] = a;
  t[1] = b;
  bf16x2 h = __builtin_convertvector(t, bf16x2);
  return __builtin_bit_cast(uint32_t, h);
}

__device__ __forceinline__ u16 f2b(float f) {
  return __builtin_bit_cast(u16, (__bf16)f);
}

// RNE f32x4 (scaled) -> 4 packed bf16 (2x v_cvt_pk_bf16_f32)
__device__ __forceinline__ uint2 pkbf16x4(f32x4 v, float s) {
  uint2 r;
  r.x = pk2(v[0] * s, v[1] * s);
  r.y = pk2(v[2] * s, v[3] * s);
  return r;
}

// async global->LDS, 16B per lane. LDS dest = wave-uniform base + lane*16.
__device__ __forceinline__ void dma16(const u16* g, u16* l) {
  __builtin_amdgcn_global_load_lds(
      (const __attribute__((address_space(1))) unsigned int*)(uintptr_t)g,
      (__attribute__((address_space(3))) unsigned int*)(uintptr_t)l, 16, 0, 0);
}

#define LDS_FENCE() asm volatile("s_waitcnt lgkmcnt(0)" ::: "memory")

// ---------------- fused: x fp32->bf16 cast + weight transposes -----------
// blocks [0,4096): xcast. blocks [4096,4352): transpose (64 tiles x 4 mtx).
__global__ __launch_bounds__(256) void xcast_tr(const float* __restrict__ x,
                                                u16* __restrict__ xb,
                                                const float* __restrict__ wq,
                                                const float* __restrict__ wk,
                                                const float* __restrict__ wv,
                                                const float* __restrict__ wo,
                                                u16* __restrict__ wT,
                                                u16* __restrict__ woT) {
  __shared__ __align__(16) u16 T[64][68];
  const int tid = threadIdx.x;
  if (blockIdx.x < 4096) {
    const size_t i = (size_t)(blockIdx.x * 256 + tid) * 8;
    const float4 a = *(const float4*)(x + i);
    const float4 b = *(const float4*)(x + i + 4);
    uint4 o;
    o.x = pk2(a.x, a.y);
    o.y = pk2(a.z, a.w);
    o.z = pk2(b.x, b.y);
    o.w = pk2(b.z, b.w);
    *(uint4*)(xb + i) = o;
    return;
  }
  const int bid2 = blockIdx.x - 4096;
  const int mtx = bid2 >> 6, t = bid2 & 63;
  const float* src = (mtx == 0) ? wq : (mtx == 1) ? wk : (mtx == 2) ? wv : wo;
  u16* dst = (mtx < 3) ? (wT + (size_t)mtx * 262144) : woT;
  const int tr = t >> 3, tc = t & 7;
#pragma unroll
  for (int p = 0; p < 4; ++p) {
    int i = p * 256 + tid;
    int row = i >> 4, c4 = i & 15;
    float4 v = *(const float4*)(src + (size_t)(tr * 64 + row) * 512 + tc * 64 + c4 * 4);
    T[c4 * 4 + 0][row] = f2b(v.x);
    T[c4 * 4 + 1][row] = f2b(v.y);
    T[c4 * 4 + 2][row] = f2b(v.z);
    T[c4 * 4 + 3][row] = f2b(v.w);
  }
  __syncthreads();
#pragma unroll
  for (int p = 0; p < 4; ++p) {
    int i = p * 256 + tid;
    int row = i >> 4, c4 = i & 15;
    *(u16x4*)(dst + (size_t)(tc * 64 + row) * 512 + tr * 64 + c4 * 4) =
        *(const u16x4*)&T[row][c4 * 4];
  }
}

// ---------------- QKV projection GEMM ------------------------------------
// R12: __launch_bounds__(512,6) -> VGPR cap 85 (usage ~75, no spill) ->
// guaranteed 3 blocks/CU (36 KB LDS x3 = 108 KB fits). Grid 1536 = 2 EXACT
// rounds at 3/CU (was 3 rounds at 2/CU). 8 waves as 4m x 2n, acc[2][4].
// dma16 staging, XOR chunk swizzle (as R8-R11).
__global__ __launch_bounds__(512, 6) void qkv_gemm(const u16* __restrict__ xb,
                                                   const u16* __restrict__ wT_all,
                                                   u16* __restrict__ qbuf,
                                                   u16* __restrict__ kbuf,
                                                   u16* __restrict__ vtbuf) {
  __shared__ __align__(16) u16 smem[18432];  // staging 32 KB; epilogue 36 KB
  u16* As = smem;              // [128][64] swizzled (s rows)
  u16* Bs = smem + 128 * 64;   // [128][64] swizzled (dh rows)
  const int tid = threadIdx.x;
  const int wave = tid >> 6, lane = tid & 63, quad = lane >> 4, l16 = lane & 15;
  const int wm = wave >> 1, wn = wave & 1;
  const int ldrow = lane >> 3;        // 0..7 (== row&7 of the staged row)
  const int ldcs = ((lane & 7) ^ ldrow) * 8;   // pre-swizzled global chunk
  const int m0 = blockIdx.x * 128;
  const int which = blockIdx.y >> 2;            // 0=q 1=k 2=v
  const int n0 = (blockIdx.y & 3) * 128;        // dh offset within which
  const u16* wTb = wT_all + (size_t)which * 262144 + (size_t)n0 * 512;

  f32x4 acc[2][4];
  const f32x4 fz = {0.f, 0.f, 0.f, 0.f};
#pragma unroll
  for (int i = 0; i < 2; ++i)
#pragma unroll
    for (int j = 0; j < 4; ++j) acc[i][j] = fz;

  for (int k0 = 0; k0 < 512; k0 += 64) {
#pragma unroll
    for (int p = 0; p < 2; ++p) {
      const int row = (p * 8 + wave) * 8 + ldrow;
      dma16(xb + (size_t)(m0 + row) * 512 + k0 + ldcs, As + (p * 8 + wave) * 512);
    }
#pragma unroll
    for (int p = 0; p < 2; ++p) {
      const int row = (p * 8 + wave) * 8 + ldrow;
      dma16(wTb + (size_t)row * 512 + k0 + ldcs, Bs + (p * 8 + wave) * 512);
    }
    __syncthreads();   // drains vmcnt -> chunk resident
#pragma unroll
    for (int ks = 0; ks < 2; ++ks) {
      short8 xf[2], wf[4];
#pragma unroll
      for (int mt = 0; mt < 2; ++mt)
        xf[mt] = *(const short8*)&As[(wm * 32 + mt * 16 + l16) * 64 +
                                     ((ks * 32 + quad * 8) ^ ((l16 & 7) * 8))];
#pragma unroll
      for (int nt = 0; nt < 4; ++nt)
        wf[nt] = *(const short8*)&Bs[(wn * 64 + nt * 16 + l16) * 64 +
                                     ((ks * 32 + quad * 8) ^ ((l16 & 7) * 8))];
      if (which < 2) {
#pragma unroll
        for (int mt = 0; mt < 2; ++mt)
#pragma unroll
          for (int nt = 0; nt < 4; ++nt)
            acc[mt][nt] = __builtin_amdgcn_mfma_f32_16x16x32_bf16(wf[nt], xf[mt],
                                                                  acc[mt][nt], 0, 0, 0);
      } else {
#pragma unroll
        for (int mt = 0; mt < 2; ++mt)
#pragma unroll
          for (int nt = 0; nt < 4; ++nt)
            acc[mt][nt] = __builtin_amdgcn_mfma_f32_16x16x32_bf16(xf[mt], wf[nt],
                                                                  acc[mt][nt], 0, 0, 0);
      }
    }
    __syncthreads();   // readers done before next chunk overwrites
  }
  // Per-wave private smem slice (2304 u16).
  u16* sw = smem + wave * 2304;
  const int dhg0 = n0 + wn * 64;
  const int h = dhg0 >> 7, dhh0 = dhg0 & 127;
  const int bq = m0 >> 12;
  const int bh = bq * 4 + h;
  const int sl0 = (m0 & 4095) + wm * 32;

  if (which < 2) {
    const float scl = (which == 0) ? 0.08838834764831845f : 1.0f;  // DH^-0.5 on q
    u16* dst = (which == 0) ? qbuf : kbuf;
#pragma unroll
    for (int mt = 0; mt < 2; ++mt) {
      LDS_FENCE();  // prior readback done before overwrite
#pragma unroll
      for (int nt = 0; nt < 4; ++nt)
        *(uint2*)&sw[l16 * 68 + nt * 16 + quad * 4] = pkbf16x4(acc[mt][nt], scl);
      LDS_FENCE();
#pragma unroll
      for (int p = 0; p < 2; ++p) {
        const int sr = p * 8 + (lane >> 3), dl = (lane & 7) * 8;
        uint4 v = *(const uint4*)&sw[sr * 68 + dl];
        const int sl = sl0 + mt * 16 + sr;
        *(uint4*)(dst + ((size_t)(bh * 4096 + sl)) * 128 + dhh0 + dl) = v;
      }
    }
  } else {
    // v: scratch [64 dh][32 s + pad4], single pass (wave owns 32 s)
    LDS_FENCE();
#pragma unroll
    for (int mt = 0; mt < 2; ++mt)
#pragma unroll
      for (int nt = 0; nt < 4; ++nt)
        *(uint2*)&sw[(nt * 16 + l16) * 36 + mt * 16 + quad * 4] =
            pkbf16x4(acc[mt][nt], 1.0f);
    LDS_FENCE();
#pragma unroll
    for (int j = 0; j < 4; ++j) {
      const int dl = j * 16 + (lane >> 2), so = (lane & 3) * 8;
      uint4 v = *(const uint4*)&sw[dl * 36 + so];
      const int sl = sl0 + so;
      *(uint4*)(vtbuf + ((size_t)(bh * 128 + dhh0 + dl)) * 4096 + sl) = v;
    }
  }
}

// ---------------- causal flash attention, balanced split-K jobs ----------
// R10 structure + wave-uniform diag branch (R9's good half alone): kt==r is
// wave-uniform, so the mask cmp+cndmask runs only on the diagonal tile
// (~3% of tiles) instead of every tile. l_run stays on the VALU path
// (R9 showed MFMA-l costs more MFMA than it saves VALU).
__global__ __launch_bounds__(128, 2) void attn(const u16* __restrict__ qbuf,
                                               const u16* __restrict__ kbuf,
                                               const u16* __restrict__ vtbuf,
                                               const float* __restrict__ rel_row,
                                               const float* __restrict__ rel_col,
                                               u16* __restrict__ obuf,
                                               float* __restrict__ opart,
                                               float* __restrict__ lpart) {
  __shared__ __align__(16) u16 KsF[64 * 128];   // [key][dh], col ^= (row&7)*8
  __shared__ __align__(16) u16 VtF[128 * 64];   // [dh][key], col ^= (row&7)*8
#ifndef HAVE_MFMA16
  __shared__ __align__(16) u16 Plds[2][2][16][72];
#endif
  __shared__ float rcol[128];
  __shared__ float rrow[128];

  const int tid = threadIdx.x;
  const int wave = tid >> 6, lane = tid & 63, quad = lane >> 4, l16 = lane & 15;
  const int jid = blockIdx.x;
  const int bh = jid & 15, p = (jid >> 4) & 31, half = jid >> 9;
  const int b = bh >> 2, h = bh & 3;

  const float LOG2E = 1.4426950408889634f;
  rcol[tid] = rel_col[h * 128 + tid] * LOG2E;
  rrow[tid] = rel_row[h * 128 + tid] * LOG2E;

  const int q0 = wave * 32 + l16;           // g adds +16

  __syncthreads();   // rcol/rrow visible

  float rc2[2][4][4];
#pragma unroll
  for (int g = 0; g < 2; ++g)
#pragma unroll
    for (int nt = 0; nt < 4; ++nt)
#pragma unroll
      for (int r = 0; r < 4; ++r)
        rc2[g][nt][r] = rcol[63 + nt * 16 + quad * 4 + r - (q0 + g * 16)];

  const f32x4 fz = {0.f, 0.f, 0.f, 0.f};
  const u16* kbase = kbuf + (size_t)bh * 4096 * 128;
  const u16* vbase = vtbuf + (size_t)bh * 128 * 4096;
  // staging coords (8 rounds K + 8 rounds V per tile, 1 KB/round/wave);
  // global col pre-swizzled so the linear LDS fill lands swizzled rows.
  const int krow = wave * 4 + (lane >> 4);            // 0..7
  const int kcs = ((lane & 15) ^ krow) * 8;
  const int vrow = wave * 8 + (lane >> 3);            // 0..15
  const int vcs = ((lane & 7) ^ (vrow & 7)) * 8;

  auto run_row = [&](int r, int ktb, int kte, bool direct) {
    const u16* qrow0 = qbuf + ((size_t)bh * 4096 + r * 64 + q0) * 128;
    short8 qf[2][4];
#pragma unroll
    for (int g = 0; g < 2; ++g)
#pragma unroll
      for (int ks = 0; ks < 4; ++ks)
        qf[g][ks] = *(const short8*)(qrow0 + (size_t)g * 16 * 128 + ks * 32 + quad * 8);
    f32x4 oacc[2][8];
#pragma unroll
    for (int g = 0; g < 2; ++g)
#pragma unroll
      for (int i = 0; i < 8; ++i) oacc[g][i] = fz;
    float l_run[2] = {0.0f, 0.0f};

    for (int kt = ktb; kt < kte; ++kt) {
      __syncthreads();   // all waves done reading previous tile
      {
        const u16* ksrc = kbase + (size_t)kt * 8192;
        const u16* vsrc = vbase + (size_t)kt * 64;
        u16* kd = KsF + wave * 512;
        u16* vd = VtF + wave * 512;
#pragma unroll
        for (int j = 0; j < 8; ++j)
          dma16(ksrc + (size_t)(j * 8 + krow) * 128 + kcs, kd + j * 1024);
#pragma unroll
        for (int j = 0; j < 8; ++j)
          dma16(vsrc + (size_t)(j * 16 + vrow) * 4096 + vcs, vd + j * 1024);
      }
      __syncthreads();   // drains vmcnt -> tile resident

      // Sᵀ tiles: rows = key (nt), cols = q (l16); each kf feeds both g.
      f32x4 sacc[2][4];
#pragma unroll
      for (int g = 0; g < 2; ++g)
#pragma unroll
        for (int nt = 0; nt < 4; ++nt) sacc[g][nt] = fz;
      __builtin_amdgcn_s_setprio(1);
#pragma unroll
      for (int ks = 0; ks < 4; ++ks)
#pragma unroll
        for (int nt = 0; nt < 4; ++nt) {
          short8 kf = *(const short8*)&KsF[(nt * 16 + l16) * 128 +
                                           ((ks * 32 + quad * 8) ^ ((l16 & 7) * 8))];
          sacc[0][nt] = __builtin_amdgcn_mfma_f32_16x16x32_bf16(kf, qf[0][ks], sacc[0][nt], 0, 0, 0);
          sacc[1][nt] = __builtin_amdgcn_mfma_f32_16x16x32_bf16(kf, qf[1][ks], sacc[1][nt], 0, 0, 0);
        }
      __builtin_amdgcn_s_setprio(0);

      const float browl = rrow[63 + kt - r];
      uint2 pd[2][4];
      if (kt == r) {   // diagonal tile: future mask (wave-uniform branch)
#pragma unroll
        for (int g = 0; g < 2; ++g) {
          const int qc = q0 + g * 16;
#pragma unroll
          for (int nt = 0; nt < 4; ++nt) {
            f32x4 pv;
#pragma unroll
            for (int rr = 0; rr < 4; ++rr) {
              const int kc2 = nt * 16 + quad * 4 + rr;
              float pe = __builtin_amdgcn_exp2f(fmaf(sacc[g][nt][rr], LOG2E, rc2[g][nt][rr] + browl));
              if (kc2 > qc) pe = 0.0f;
              l_run[g] += pe;
              pv[rr] = pe;
            }
            pd[g][nt].x = pk2(pv[0], pv[1]);
            pd[g][nt].y = pk2(pv[2], pv[3]);
          }
        }
      } else {
#pragma unroll
        for (int g = 0; g < 2; ++g)
#pragma unroll
          for (int nt = 0; nt < 4; ++nt) {
            f32x4 pv;
#pragma unroll
            for (int rr = 0; rr < 4; ++rr) {
              float pe = __builtin_amdgcn_exp2f(fmaf(sacc[g][nt][rr], LOG2E, rc2[g][nt][rr] + browl));
              l_run[g] += pe;
              pv[rr] = pe;
            }
            pd[g][nt].x = pk2(pv[0], pv[1]);
            pd[g][nt].y = pk2(pv[2], pv[3]);
          }
      }

#ifdef HAVE_MFMA16
      // Oᵀ += Vᵀ·Pᵀ with K=16 MFMA; each vf feeds both g.
      __builtin_amdgcn_s_setprio(1);
#pragma unroll
      for (int nt = 0; nt < 4; ++nt) {
        short4v pf0 = __builtin_bit_cast(short4v, pd[0][nt]);
        short4v pf1 = __builtin_bit_cast(short4v, pd[1][nt]);
#pragma unroll
        for (int mt = 0; mt < 8; ++mt) {
          short4v vf = *(const short4v*)&VtF[(mt * 16 + l16) * 64 +
                                             ((nt * 16 + quad * 4) ^ ((l16 & 7) * 8))];
          oacc[0][mt] = __builtin_amdgcn_mfma_f32_16x16x16bf16_1k(vf, pf0, oacc[0][mt], 0, 0, 0);
          oacc[1][mt] = __builtin_amdgcn_mfma_f32_16x16x16bf16_1k(vf, pf1, oacc[1][mt], 0, 0, 0);
        }
      }
      __builtin_amdgcn_s_setprio(0);
#else
#pragma unroll
      for (int g = 0; g < 2; ++g)
#pragma unroll
        for (int nt = 0; nt < 4; ++nt)
          *(uint2*)&Plds[wave][g][l16][nt * 16 + quad * 4] = pd[g][nt];
#pragma unroll
      for (int g = 0; g < 2; ++g)
#pragma unroll
        for (int ks2 = 0; ks2 < 2; ++ks2) {
          short8 pf = *(const short8*)&Plds[wave][g][l16][ks2 * 32 + quad * 8];
#pragma unroll
          for (int mt = 0; mt < 8; ++mt) {
            short8 vf = *(const short8*)&VtF[(mt * 16 + l16) * 64 +
                                             ((ks2 * 32 + quad * 8) ^ ((l16 & 7) * 8))];
            oacc[g][mt] = __builtin_amdgcn_mfma_f32_16x16x32_bf16(vf, pf, oacc[g][mt], 0, 0, 0);
          }
        }
#endif
    }

#pragma unroll
    for (int g = 0; g < 2; ++g) {
      l_run[g] += __shfl_xor(l_run[g], 16);
      l_run[g] += __shfl_xor(l_run[g], 32);
    }
    if (direct) {
#pragma unroll
      for (int g = 0; g < 2; ++g) {
        const float inv_l = 1.0f / l_run[g];
        u16* orow = obuf + ((size_t)b * 4096 + r * 64 + q0 + g * 16) * 512 + h * 128;
#pragma unroll
        for (int mt = 0; mt < 8; ++mt)
          *(uint2*)(orow + mt * 16 + quad * 4) = pkbf16x4(oacc[g][mt], inv_l);
      }
    } else {
#pragma unroll
      for (int g = 0; g < 2; ++g) {
        const size_t qi = (size_t)((half * 16 + bh) * 32 + (r - 32)) * 64 + q0 + g * 16;
        float* od = opart + qi * 128;
#pragma unroll
        for (int mt = 0; mt < 8; ++mt)
          *(f32x4*)(od + mt * 16 + quad * 4) = oacc[g][mt];
        if (quad == 0) lpart[qi] = l_run[g];
      }
    }
  };

  if (half == 0) {
    run_row(p, 0, p + 1, true);          // row A complete (incl. diagonal)
    run_row(63 - p, 0, 32 - p, false);   // row B lower partial
  } else {
    run_row(63 - p, 32 - p, 64 - p, false);  // row B upper partial (incl. diag)
  }
}

// ---------------- combine row-B partials + normalize ---------------------
__global__ __launch_bounds__(256) void onorm(const float* __restrict__ opart,
                                             const float* __restrict__ lpart,
                                             u16* __restrict__ obuf) {
  const int gi = blockIdx.x * 256 + threadIdx.x;   // 524288 total
  const int d8 = (gi & 15) * 8;
  const int qi = gi >> 4;                          // (bh*32+rr)*64+q
  const int q = qi & 63, rr = (qi >> 6) & 31, bh = qi >> 11;
  const float inv = 1.0f / (lpart[qi] + lpart[32768 + qi]);
  const float* s0 = opart + (size_t)qi * 128 + d8;
  const float* s1 = s0 + 4194304;                  // second half slot
  f32x4 a0 = *(const f32x4*)s0;
  f32x4 b0 = *(const f32x4*)(s0 + 4);
  f32x4 a1 = *(const f32x4*)s1;
  f32x4 b1 = *(const f32x4*)(s1 + 4);
  f32x4 sa = a0 + a1, sb = b0 + b1;
  uint4 o;
  o.x = pk2(sa[0] * inv, sa[1] * inv);
  o.y = pk2(sa[2] * inv, sa[3] * inv);
  o.z = pk2(sb[0] * inv, sb[1] * inv);
  o.w = pk2(sb[2] * inv, sb[3] * inv);
  const int b = bh >> 2, h = bh & 3;
  const int q_glob = (32 + rr) * 64 + q;
  *(uint4*)(obuf + ((size_t)b * 4096 + q_glob) * 512 + h * 128 + d8) = o;
}

// ---------------- output projection GEMM ---------------------------------
// N=128 -> grid 128x4 = 512 blocks = exact 2-blocks/CU fill. 8 waves as
// 4m x 2n, acc[2][4]. dma16 staging, same swizzle.
__global__ __launch_bounds__(512, 4) void out_gemm(const u16* __restrict__ obuf,
                                                   const u16* __restrict__ woT,
                                                   float* __restrict__ out) {
  __shared__ __align__(16) u16 smem[18432];  // staging 32 KB; f32 epilogue 36 KB
  u16* As = smem;              // [128][64] obuf rows (s), swizzled
  u16* Bs = smem + 128 * 64;   // [128][64] woT rows (d), swizzled
  const int tid = threadIdx.x;
  const int wave = tid >> 6, lane = tid & 63, quad = lane >> 4, l16 = lane & 15;
  const int wm = wave >> 1, wn = wave & 1;
  const int ldrow = lane >> 3;
  const int ldcs = ((lane & 7) ^ ldrow) * 8;
  const int m0 = blockIdx.x * 128;
  const int n0 = blockIdx.y * 128;

  f32x4 acc[2][4];
  const f32x4 fz = {0.f, 0.f, 0.f, 0.f};
#pragma unroll
  for (int i = 0; i < 2; ++i)
#pragma unroll
    for (int j = 0; j < 4; ++j) acc[i][j] = fz;

  for (int k0 = 0; k0 < 512; k0 += 64) {
#pragma unroll
    for (int p = 0; p < 2; ++p) {
      const int row = (p * 8 + wave) * 8 + ldrow;
      dma16(obuf + (size_t)(m0 + row) * 512 + k0 + ldcs, As + (p * 8 + wave) * 512);
    }
#pragma unroll
    for (int p = 0; p < 2; ++p) {
      const int row = (p * 8 + wave) * 8 + ldrow;
      dma16(woT + (size_t)(n0 + row) * 512 + k0 + ldcs, Bs + (p * 8 + wave) * 512);
    }
    __syncthreads();
#pragma unroll
    for (int ks = 0; ks < 2; ++ks) {
      short8 of[2], wf[4];
#pragma unroll
      for (int mt = 0; mt < 2; ++mt)
        of[mt] = *(const short8*)&As[(wm * 32 + mt * 16 + l16) * 64 +
                                     ((ks * 32 + quad * 8) ^ ((l16 & 7) * 8))];
#pragma unroll
      for (int nt = 0; nt < 4; ++nt)
        wf[nt] = *(const short8*)&Bs[(wn * 64 + nt * 16 + l16) * 64 +
                                     ((ks * 32 + quad * 8) ^ ((l16 & 7) * 8))];
#pragma unroll
      for (int mt = 0; mt < 2; ++mt)
#pragma unroll
        for (int nt = 0; nt < 4; ++nt)
          acc[mt][nt] = __builtin_amdgcn_mfma_f32_16x16x32_bf16(wf[nt], of[mt],
                                                                acc[mt][nt], 0, 0, 0);
    }
    __syncthreads();
  }

  float* swf = (float*)smem + wave * 1152;   // per-wave [16 s][68 d] f32
#pragma unroll
  for (int mt = 0; mt < 2; ++mt) {
    LDS_FENCE();
#pragma unroll
    for (int nt = 0; nt < 4; ++nt)
      *(f32x4*)&swf[l16 * 68 + nt * 16 + quad * 4] = acc[mt][nt];
    LDS_FENCE();
#pragma unroll
    for (int p = 0; p < 4; ++p) {
      const int sr = p * 4 + (lane >> 4), dl = l16 * 4;
      float4 v = *(const float4*)&swf[sr * 68 + dl];
      const int s = m0 + wm * 32 + mt * 16 + sr;
      *(float4*)(out + (size_t)s * 512 + n0 + wn * 64 + dl) = v;
    }
  }
}

// ---------------- launch --------------------------------------------------
extern "C" void kernel_launch(void* const* d_in, const int* in_sizes, int n_in,
                              void* d_out, int out_size, void* d_ws, size_t ws_size,
                              hipStream_t stream) {
  const float* x       = (const float*)d_in[0];
  const float* wq      = (const float*)d_in[1];
  const float* wk      = (const float*)d_in[2];
  const float* wv      = (const float*)d_in[3];
  const float* wo      = (const float*)d_in[4];
  const float* rel_row = (const float*)d_in[5];
  const float* rel_col = (const float*)d_in[6];
  float* out = (float*)d_out;

  char* ws = (char*)d_ws;
  u16* wT    = (u16*)(ws);                               // 3 * 512*512 bf16
  u16* woT   = (u16*)(ws + 1572864);                     // 512*512 bf16
  u16* qbuf  = (u16*)(ws + 2097152);                     // 16 MiB
  u16* kbuf  = (u16*)(ws + 2097152 + 16777216);          // 16 MiB
  u16* vtbuf = (u16*)(ws + 2097152 + 2 * 16777216);      // 16 MiB
  u16* obuf  = (u16*)(ws + 2097152 + 3 * 16777216);      // 16 MiB
  float* opart = (float*)(ws + 2097152 + 4 * 16777216);  // 32 MiB (2 slots)
  float* lpart = (float*)(ws + 2097152 + 6 * 16777216);  // 256 KiB (2 slots)
  u16* xb    = obuf;  // xb consumed by qkv_gemm before attn writes obuf

  xcast_tr<<<4352, 256, 0, stream>>>(x, xb, wq, wk, wv, wo, wT, woT);
  qkv_gemm<<<dim3(128, 12), 512, 0, stream>>>(xb, wT, qbuf, kbuf, vtbuf);
  attn<<<1024, 128, 0, stream>>>(qbuf, kbuf, vtbuf, rel_row, rel_col, obuf, opart, lpart);
  onorm<<<2048, 256, 0, stream>>>(opart, lpart, obuf);
  out_gemm<<<dim3(128, 4), 512, 0, stream>>>(obuf, woT, out);
}

// Round 13
// 256.945 us; speedup vs baseline: 1.4806x; 1.4806x over previous
//
#include <hip/hip_runtime.h>
#include <cstdint>

typedef unsigned short u16;
typedef __attribute__((ext_vector_type(8))) short short8;
typedef __attribute__((ext_vector_type(4))) short short4v;
typedef __attribute__((ext_vector_type(4))) float f32x4;
typedef __attribute__((ext_vector_type(4))) unsigned short u16x4;
typedef __attribute__((ext_vector_type(2))) float f32x2;
typedef __attribute__((ext_vector_type(2))) __bf16 bf16x2;

// B=4 R=64 C=64 D=512 H=4 DH=128 S=4096, M = B*S = 16384

#if defined(__has_builtin)
#if __has_builtin(__builtin_amdgcn_mfma_f32_16x16x16bf16_1k)
#define HAVE_MFMA16 1
#endif
#endif

// HW packed f32->bf16 (RNE): single v_cvt_pk_bf16_f32.
__device__ __forceinline__ uint32_t pk2(float a, float b) {
  f32x2 t;
  t[0] = a;
  t[1] = b;
  bf16x2 h = __builtin_convertvector(t, bf16x2);
  return __builtin_bit_cast(uint32_t, h);
}

__device__ __forceinline__ u16 f2b(float f) {
  return __builtin_bit_cast(u16, (__bf16)f);
}

// RNE f32x4 (scaled) -> 4 packed bf16 (2x v_cvt_pk_bf16_f32)
__device__ __forceinline__ uint2 pkbf16x4(f32x4 v, float s) {
  uint2 r;
  r.x = pk2(v[0] * s, v[1] * s);
  r.y = pk2(v[2] * s, v[3] * s);
  return r;
}

// async global->LDS, 16B per lane. LDS dest = wave-uniform base + lane*16.
__device__ __forceinline__ void dma16(const u16* g, u16* l) {
  __builtin_amdgcn_global_load_lds(
      (const __attribute__((address_space(1))) unsigned int*)(uintptr_t)g,
      (__attribute__((address_space(3))) unsigned int*)(uintptr_t)l, 16, 0, 0);
}

#define LDS_FENCE() asm volatile("s_waitcnt lgkmcnt(0)" ::: "memory")

// ---------------- fused: x fp32->bf16 cast + weight transposes -----------
// blocks [0,4096): xcast. blocks [4096,4352): transpose (64 tiles x 4 mtx).
__global__ __launch_bounds__(256) void xcast_tr(const float* __restrict__ x,
                                                u16* __restrict__ xb,
                                                const float* __restrict__ wq,
                                                const float* __restrict__ wk,
                                                const float* __restrict__ wv,
                                                const float* __restrict__ wo,
                                                u16* __restrict__ wT,
                                                u16* __restrict__ woT) {
  __shared__ __align__(16) u16 T[64][68];
  const int tid = threadIdx.x;
  if (blockIdx.x < 4096) {
    const size_t i = (size_t)(blockIdx.x * 256 + tid) * 8;
    const float4 a = *(const float4*)(x + i);
    const float4 b = *(const float4*)(x + i + 4);
    uint4 o;
    o.x = pk2(a.x, a.y);
    o.y = pk2(a.z, a.w);
    o.z = pk2(b.x, b.y);
    o.w = pk2(b.z, b.w);
    *(uint4*)(xb + i) = o;
    return;
  }
  const int bid2 = blockIdx.x - 4096;
  const int mtx = bid2 >> 6, t = bid2 & 63;
  const float* src = (mtx == 0) ? wq : (mtx == 1) ? wk : (mtx == 2) ? wv : wo;
  u16* dst = (mtx < 3) ? (wT + (size_t)mtx * 262144) : woT;
  const int tr = t >> 3, tc = t & 7;
#pragma unroll
  for (int p = 0; p < 4; ++p) {
    int i = p * 256 + tid;
    int row = i >> 4, c4 = i & 15;
    float4 v = *(const float4*)(src + (size_t)(tr * 64 + row) * 512 + tc * 64 + c4 * 4);
    T[c4 * 4 + 0][row] = f2b(v.x);
    T[c4 * 4 + 1][row] = f2b(v.y);
    T[c4 * 4 + 2][row] = f2b(v.z);
    T[c4 * 4 + 3][row] = f2b(v.w);
  }
  __syncthreads();
#pragma unroll
  for (int p = 0; p < 4; ++p) {
    int i = p * 256 + tid;
    int row = i >> 4, c4 = i & 15;
    *(u16x4*)(dst + (size_t)(tc * 64 + row) * 512 + tr * 64 + c4 * 4) =
        *(const u16x4*)&T[row][c4 * 4];
  }
}

// ---------------- QKV projection GEMM ------------------------------------
// R11-exact (measured good). N=128 units, grid 128x12 = 1536 blocks = 3
// rounds at 2 blocks/CU. 8 waves as 4m x 2n, acc[2][4]. dma16 staging,
// XOR chunk swizzle. __launch_bounds__(512,4): R12 proved (512,6) forces
// a 40-VGPR allocation and catastrophic spill (WRITE_SIZE 422 MB) — never
// cap below measured VGPR_Count.
__global__ __launch_bounds__(512, 4) void qkv_gemm(const u16* __restrict__ xb,
                                                   const u16* __restrict__ wT_all,
                                                   u16* __restrict__ qbuf,
                                                   u16* __restrict__ kbuf,
                                                   u16* __restrict__ vtbuf) {
  __shared__ __align__(16) u16 smem[18432];  // staging 32 KB; epilogue 36 KB
  u16* As = smem;              // [128][64] swizzled (s rows)
  u16* Bs = smem + 128 * 64;   // [128][64] swizzled (dh rows)
  const int tid = threadIdx.x;
  const int wave = tid >> 6, lane = tid & 63, quad = lane >> 4, l16 = lane & 15;
  const int wm = wave >> 1, wn = wave & 1;
  const int ldrow = lane >> 3;        // 0..7 (== row&7 of the staged row)
  const int ldcs = ((lane & 7) ^ ldrow) * 8;   // pre-swizzled global chunk
  const int m0 = blockIdx.x * 128;
  const int which = blockIdx.y >> 2;            // 0=q 1=k 2=v
  const int n0 = (blockIdx.y & 3) * 128;        // dh offset within which
  const u16* wTb = wT_all + (size_t)which * 262144 + (size_t)n0 * 512;

  f32x4 acc[2][4];
  const f32x4 fz = {0.f, 0.f, 0.f, 0.f};
#pragma unroll
  for (int i = 0; i < 2; ++i)
#pragma unroll
    for (int j = 0; j < 4; ++j) acc[i][j] = fz;

  for (int k0 = 0; k0 < 512; k0 += 64) {
#pragma unroll
    for (int p = 0; p < 2; ++p) {
      const int row = (p * 8 + wave) * 8 + ldrow;
      dma16(xb + (size_t)(m0 + row) * 512 + k0 + ldcs, As + (p * 8 + wave) * 512);
    }
#pragma unroll
    for (int p = 0; p < 2; ++p) {
      const int row = (p * 8 + wave) * 8 + ldrow;
      dma16(wTb + (size_t)row * 512 + k0 + ldcs, Bs + (p * 8 + wave) * 512);
    }
    __syncthreads();   // drains vmcnt -> chunk resident
#pragma unroll
    for (int ks = 0; ks < 2; ++ks) {
      short8 xf[2], wf[4];
#pragma unroll
      for (int mt = 0; mt < 2; ++mt)
        xf[mt] = *(const short8*)&As[(wm * 32 + mt * 16 + l16) * 64 +
                                     ((ks * 32 + quad * 8) ^ ((l16 & 7) * 8))];
#pragma unroll
      for (int nt = 0; nt < 4; ++nt)
        wf[nt] = *(const short8*)&Bs[(wn * 64 + nt * 16 + l16) * 64 +
                                     ((ks * 32 + quad * 8) ^ ((l16 & 7) * 8))];
      if (which < 2) {
#pragma unroll
        for (int mt = 0; mt < 2; ++mt)
#pragma unroll
          for (int nt = 0; nt < 4; ++nt)
            acc[mt][nt] = __builtin_amdgcn_mfma_f32_16x16x32_bf16(wf[nt], xf[mt],
                                                                  acc[mt][nt], 0, 0, 0);
      } else {
#pragma unroll
        for (int mt = 0; mt < 2; ++mt)
#pragma unroll
          for (int nt = 0; nt < 4; ++nt)
            acc[mt][nt] = __builtin_amdgcn_mfma_f32_16x16x32_bf16(xf[mt], wf[nt],
                                                                  acc[mt][nt], 0, 0, 0);
      }
    }
    __syncthreads();   // readers done before next chunk overwrites
  }
  // Per-wave private smem slice (2304 u16).
  u16* sw = smem + wave * 2304;
  const int dhg0 = n0 + wn * 64;
  const int h = dhg0 >> 7, dhh0 = dhg0 & 127;
  const int bq = m0 >> 12;
  const int bh = bq * 4 + h;
  const int sl0 = (m0 & 4095) + wm * 32;

  if (which < 2) {
    const float scl = (which == 0) ? 0.08838834764831845f : 1.0f;  // DH^-0.5 on q
    u16* dst = (which == 0) ? qbuf : kbuf;
#pragma unroll
    for (int mt = 0; mt < 2; ++mt) {
      LDS_FENCE();  // prior readback done before overwrite
#pragma unroll
      for (int nt = 0; nt < 4; ++nt)
        *(uint2*)&sw[l16 * 68 + nt * 16 + quad * 4] = pkbf16x4(acc[mt][nt], scl);
      LDS_FENCE();
#pragma unroll
      for (int p = 0; p < 2; ++p) {
        const int sr = p * 8 + (lane >> 3), dl = (lane & 7) * 8;
        uint4 v = *(const uint4*)&sw[sr * 68 + dl];
        const int sl = sl0 + mt * 16 + sr;
        *(uint4*)(dst + ((size_t)(bh * 4096 + sl)) * 128 + dhh0 + dl) = v;
      }
    }
  } else {
    // v: scratch [64 dh][32 s + pad4], single pass (wave owns 32 s)
    LDS_FENCE();
#pragma unroll
    for (int mt = 0; mt < 2; ++mt)
#pragma unroll
      for (int nt = 0; nt < 4; ++nt)
        *(uint2*)&sw[(nt * 16 + l16) * 36 + mt * 16 + quad * 4] =
            pkbf16x4(acc[mt][nt], 1.0f);
    LDS_FENCE();
#pragma unroll
    for (int j = 0; j < 4; ++j) {
      const int dl = j * 16 + (lane >> 2), so = (lane & 3) * 8;
      uint4 v = *(const uint4*)&sw[dl * 36 + so];
      const int sl = sl0 + so;
      *(uint4*)(vtbuf + ((size_t)(bh * 128 + dhh0 + dl)) * 4096 + sl) = v;
    }
  }
}

// ---------------- causal flash attention, balanced split-K jobs ----------
// R10 structure + wave-uniform diag branch: kt==r is wave-uniform, so the
// mask cmp+cndmask runs only on the diagonal tile (~3% of tiles).
// l_run stays on the VALU path (R9: MFMA-l costs more than it saves).
__global__ __launch_bounds__(128, 2) void attn(const u16* __restrict__ qbuf,
                                               const u16* __restrict__ kbuf,
                                               const u16* __restrict__ vtbuf,
                                               const float* __restrict__ rel_row,
                                               const float* __restrict__ rel_col,
                                               u16* __restrict__ obuf,
                                               float* __restrict__ opart,
                                               float* __restrict__ lpart) {
  __shared__ __align__(16) u16 KsF[64 * 128];   // [key][dh], col ^= (row&7)*8
  __shared__ __align__(16) u16 VtF[128 * 64];   // [dh][key], col ^= (row&7)*8
#ifndef HAVE_MFMA16
  __shared__ __align__(16) u16 Plds[2][2][16][72];
#endif
  __shared__ float rcol[128];
  __shared__ float rrow[128];

  const int tid = threadIdx.x;
  const int wave = tid >> 6, lane = tid & 63, quad = lane >> 4, l16 = lane & 15;
  const int jid = blockIdx.x;
  const int bh = jid & 15, p = (jid >> 4) & 31, half = jid >> 9;
  const int b = bh >> 2, h = bh & 3;

  const float LOG2E = 1.4426950408889634f;
  rcol[tid] = rel_col[h * 128 + tid] * LOG2E;
  rrow[tid] = rel_row[h * 128 + tid] * LOG2E;

  const int q0 = wave * 32 + l16;           // g adds +16

  __syncthreads();   // rcol/rrow visible

  float rc2[2][4][4];
#pragma unroll
  for (int g = 0; g < 2; ++g)
#pragma unroll
    for (int nt = 0; nt < 4; ++nt)
#pragma unroll
      for (int r = 0; r < 4; ++r)
        rc2[g][nt][r] = rcol[63 + nt * 16 + quad * 4 + r - (q0 + g * 16)];

  const f32x4 fz = {0.f, 0.f, 0.f, 0.f};
  const u16* kbase = kbuf + (size_t)bh * 4096 * 128;
  const u16* vbase = vtbuf + (size_t)bh * 128 * 4096;
  // staging coords (8 rounds K + 8 rounds V per tile, 1 KB/round/wave);
  // global col pre-swizzled so the linear LDS fill lands swizzled rows.
  const int krow = wave * 4 + (lane >> 4);            // 0..7
  const int kcs = ((lane & 15) ^ krow) * 8;
  const int vrow = wave * 8 + (lane >> 3);            // 0..15
  const int vcs = ((lane & 7) ^ (vrow & 7)) * 8;

  auto run_row = [&](int r, int ktb, int kte, bool direct) {
    const u16* qrow0 = qbuf + ((size_t)bh * 4096 + r * 64 + q0) * 128;
    short8 qf[2][4];
#pragma unroll
    for (int g = 0; g < 2; ++g)
#pragma unroll
      for (int ks = 0; ks < 4; ++ks)
        qf[g][ks] = *(const short8*)(qrow0 + (size_t)g * 16 * 128 + ks * 32 + quad * 8);
    f32x4 oacc[2][8];
#pragma unroll
    for (int g = 0; g < 2; ++g)
#pragma unroll
      for (int i = 0; i < 8; ++i) oacc[g][i] = fz;
    float l_run[2] = {0.0f, 0.0f};

    for (int kt = ktb; kt < kte; ++kt) {
      __syncthreads();   // all waves done reading previous tile
      {
        const u16* ksrc = kbase + (size_t)kt * 8192;
        const u16* vsrc = vbase + (size_t)kt * 64;
        u16* kd = KsF + wave * 512;
        u16* vd = VtF + wave * 512;
#pragma unroll
        for (int j = 0; j < 8; ++j)
          dma16(ksrc + (size_t)(j * 8 + krow) * 128 + kcs, kd + j * 1024);
#pragma unroll
        for (int j = 0; j < 8; ++j)
          dma16(vsrc + (size_t)(j * 16 + vrow) * 4096 + vcs, vd + j * 1024);
      }
      __syncthreads();   // drains vmcnt -> tile resident

      // Sᵀ tiles: rows = key (nt), cols = q (l16); each kf feeds both g.
      f32x4 sacc[2][4];
#pragma unroll
      for (int g = 0; g < 2; ++g)
#pragma unroll
        for (int nt = 0; nt < 4; ++nt) sacc[g][nt] = fz;
      __builtin_amdgcn_s_setprio(1);
#pragma unroll
      for (int ks = 0; ks < 4; ++ks)
#pragma unroll
        for (int nt = 0; nt < 4; ++nt) {
          short8 kf = *(const short8*)&KsF[(nt * 16 + l16) * 128 +
                                           ((ks * 32 + quad * 8) ^ ((l16 & 7) * 8))];
          sacc[0][nt] = __builtin_amdgcn_mfma_f32_16x16x32_bf16(kf, qf[0][ks], sacc[0][nt], 0, 0, 0);
          sacc[1][nt] = __builtin_amdgcn_mfma_f32_16x16x32_bf16(kf, qf[1][ks], sacc[1][nt], 0, 0, 0);
        }
      __builtin_amdgcn_s_setprio(0);

      const float browl = rrow[63 + kt - r];
      uint2 pd[2][4];
      if (kt == r) {   // diagonal tile: future mask (wave-uniform branch)
#pragma unroll
        for (int g = 0; g < 2; ++g) {
          const int qc = q0 + g * 16;
#pragma unroll
          for (int nt = 0; nt < 4; ++nt) {
            f32x4 pv;
#pragma unroll
            for (int rr = 0; rr < 4; ++rr) {
              const int kc2 = nt * 16 + quad * 4 + rr;
              float pe = __builtin_amdgcn_exp2f(fmaf(sacc[g][nt][rr], LOG2E, rc2[g][nt][rr] + browl));
              if (kc2 > qc) pe = 0.0f;
              l_run[g] += pe;
              pv[rr] = pe;
            }
            pd[g][nt].x = pk2(pv[0], pv[1]);
            pd[g][nt].y = pk2(pv[2], pv[3]);
          }
        }
      } else {
#pragma unroll
        for (int g = 0; g < 2; ++g)
#pragma unroll
          for (int nt = 0; nt < 4; ++nt) {
            f32x4 pv;
#pragma unroll
            for (int rr = 0; rr < 4; ++rr) {
              float pe = __builtin_amdgcn_exp2f(fmaf(sacc[g][nt][rr], LOG2E, rc2[g][nt][rr] + browl));
              l_run[g] += pe;
              pv[rr] = pe;
            }
            pd[g][nt].x = pk2(pv[0], pv[1]);
            pd[g][nt].y = pk2(pv[2], pv[3]);
          }
      }

#ifdef HAVE_MFMA16
      // Oᵀ += Vᵀ·Pᵀ with K=16 MFMA; each vf feeds both g.
      __builtin_amdgcn_s_setprio(1);
#pragma unroll
      for (int nt = 0; nt < 4; ++nt) {
        short4v pf0 = __builtin_bit_cast(short4v, pd[0][nt]);
        short4v pf1 = __builtin_bit_cast(short4v, pd[1][nt]);
#pragma unroll
        for (int mt = 0; mt < 8; ++mt) {
          short4v vf = *(const short4v*)&VtF[(mt * 16 + l16) * 64 +
                                             ((nt * 16 + quad * 4) ^ ((l16 & 7) * 8))];
          oacc[0][mt] = __builtin_amdgcn_mfma_f32_16x16x16bf16_1k(vf, pf0, oacc[0][mt], 0, 0, 0);
          oacc[1][mt] = __builtin_amdgcn_mfma_f32_16x16x16bf16_1k(vf, pf1, oacc[1][mt], 0, 0, 0);
        }
      }
      __builtin_amdgcn_s_setprio(0);
#else
#pragma unroll
      for (int g = 0; g < 2; ++g)
#pragma unroll
        for (int nt = 0; nt < 4; ++nt)
          *(uint2*)&Plds[wave][g][l16][nt * 16 + quad * 4] = pd[g][nt];
#pragma unroll
      for (int g = 0; g < 2; ++g)
#pragma unroll
        for (int ks2 = 0; ks2 < 2; ++ks2) {
          short8 pf = *(const short8*)&Plds[wave][g][l16][ks2 * 32 + quad * 8];
#pragma unroll
          for (int mt = 0; mt < 8; ++mt) {
            short8 vf = *(const short8*)&VtF[(mt * 16 + l16) * 64 +
                                             ((ks2 * 32 + quad * 8) ^ ((l16 & 7) * 8))];
            oacc[g][mt] = __builtin_amdgcn_mfma_f32_16x16x32_bf16(vf, pf, oacc[g][mt], 0, 0, 0);
          }
        }
#endif
    }

#pragma unroll
    for (int g = 0; g < 2; ++g) {
      l_run[g] += __shfl_xor(l_run[g], 16);
      l_run[g] += __shfl_xor(l_run[g], 32);
    }
    if (direct) {
#pragma unroll
      for (int g = 0; g < 2; ++g) {
        const float inv_l = 1.0f / l_run[g];
        u16* orow = obuf + ((size_t)b * 4096 + r * 64 + q0 + g * 16) * 512 + h * 128;
#pragma unroll
        for (int mt = 0; mt < 8; ++mt)
          *(uint2*)(orow + mt * 16 + quad * 4) = pkbf16x4(oacc[g][mt], inv_l);
      }
    } else {
#pragma unroll
      for (int g = 0; g < 2; ++g) {
        const size_t qi = (size_t)((half * 16 + bh) * 32 + (r - 32)) * 64 + q0 + g * 16;
        float* od = opart + qi * 128;
#pragma unroll
        for (int mt = 0; mt < 8; ++mt)
          *(f32x4*)(od + mt * 16 + quad * 4) = oacc[g][mt];
        if (quad == 0) lpart[qi] = l_run[g];
      }
    }
  };

  if (half == 0) {
    run_row(p, 0, p + 1, true);          // row A complete (incl. diagonal)
    run_row(63 - p, 0, 32 - p, false);   // row B lower partial
  } else {
    run_row(63 - p, 32 - p, 64 - p, false);  // row B upper partial (incl. diag)
  }
}

// ---------------- combine row-B partials + normalize ---------------------
__global__ __launch_bounds__(256) void onorm(const float* __restrict__ opart,
                                             const float* __restrict__ lpart,
                                             u16* __restrict__ obuf) {
  const int gi = blockIdx.x * 256 + threadIdx.x;   // 524288 total
  const int d8 = (gi & 15) * 8;
  const int qi = gi >> 4;                          // (bh*32+rr)*64+q
  const int q = qi & 63, rr = (qi >> 6) & 31, bh = qi >> 11;
  const float inv = 1.0f / (lpart[qi] + lpart[32768 + qi]);
  const float* s0 = opart + (size_t)qi * 128 + d8;
  const float* s1 = s0 + 4194304;                  // second half slot
  f32x4 a0 = *(const f32x4*)s0;
  f32x4 b0 = *(const f32x4*)(s0 + 4);
  f32x4 a1 = *(const f32x4*)s1;
  f32x4 b1 = *(const f32x4*)(s1 + 4);
  f32x4 sa = a0 + a1, sb = b0 + b1;
  uint4 o;
  o.x = pk2(sa[0] * inv, sa[1] * inv);
  o.y = pk2(sa[2] * inv, sa[3] * inv);
  o.z = pk2(sb[0] * inv, sb[1] * inv);
  o.w = pk2(sb[2] * inv, sb[3] * inv);
  const int b = bh >> 2, h = bh & 3;
  const int q_glob = (32 + rr) * 64 + q;
  *(uint4*)(obuf + ((size_t)b * 4096 + q_glob) * 512 + h * 128 + d8) = o;
}

// ---------------- output projection GEMM ---------------------------------
// N=128 -> grid 128x4 = 512 blocks = exact 2-blocks/CU fill. 8 waves as
// 4m x 2n, acc[2][4]. dma16 staging, same swizzle.
__global__ __launch_bounds__(512, 4) void out_gemm(const u16* __restrict__ obuf,
                                                   const u16* __restrict__ woT,
                                                   float* __restrict__ out) {
  __shared__ __align__(16) u16 smem[18432];  // staging 32 KB; f32 epilogue 36 KB
  u16* As = smem;              // [128][64] obuf rows (s), swizzled
  u16* Bs = smem + 128 * 64;   // [128][64] woT rows (d), swizzled
  const int tid = threadIdx.x;
  const int wave = tid >> 6, lane = tid & 63, quad = lane >> 4, l16 = lane & 15;
  const int wm = wave >> 1, wn = wave & 1;
  const int ldrow = lane >> 3;
  const int ldcs = ((lane & 7) ^ ldrow) * 8;
  const int m0 = blockIdx.x * 128;
  const int n0 = blockIdx.y * 128;

  f32x4 acc[2][4];
  const f32x4 fz = {0.f, 0.f, 0.f, 0.f};
#pragma unroll
  for (int i = 0; i < 2; ++i)
#pragma unroll
    for (int j = 0; j < 4; ++j) acc[i][j] = fz;

  for (int k0 = 0; k0 < 512; k0 += 64) {
#pragma unroll
    for (int p = 0; p < 2; ++p) {
      const int row = (p * 8 + wave) * 8 + ldrow;
      dma16(obuf + (size_t)(m0 + row) * 512 + k0 + ldcs, As + (p * 8 + wave) * 512);
    }
#pragma unroll
    for (int p = 0; p < 2; ++p) {
      const int row = (p * 8 + wave) * 8 + ldrow;
      dma16(woT + (size_t)(n0 + row) * 512 + k0 + ldcs, Bs + (p * 8 + wave) * 512);
    }
    __syncthreads();
#pragma unroll
    for (int ks = 0; ks < 2; ++ks) {
      short8 of[2], wf[4];
#pragma unroll
      for (int mt = 0; mt < 2; ++mt)
        of[mt] = *(const short8*)&As[(wm * 32 + mt * 16 + l16) * 64 +
                                     ((ks * 32 + quad * 8) ^ ((l16 & 7) * 8))];
#pragma unroll
      for (int nt = 0; nt < 4; ++nt)
        wf[nt] = *(const short8*)&Bs[(wn * 64 + nt * 16 + l16) * 64 +
                                     ((ks * 32 + quad * 8) ^ ((l16 & 7) * 8))];
#pragma unroll
      for (int mt = 0; mt < 2; ++mt)
#pragma unroll
        for (int nt = 0; nt < 4; ++nt)
          acc[mt][nt] = __builtin_amdgcn_mfma_f32_16x16x32_bf16(wf[nt], of[mt],
                                                                acc[mt][nt], 0, 0, 0);
    }
    __syncthreads();
  }

  float* swf = (float*)smem + wave * 1152;   // per-wave [16 s][68 d] f32
#pragma unroll
  for (int mt = 0; mt < 2; ++mt) {
    LDS_FENCE();
#pragma unroll
    for (int nt = 0; nt < 4; ++nt)
      *(f32x4*)&swf[l16 * 68 + nt * 16 + quad * 4] = acc[mt][nt];
    LDS_FENCE();
#pragma unroll
    for (int p = 0; p < 4; ++p) {
      const int sr = p * 4 + (lane >> 4), dl = l16 * 4;
      float4 v = *(const float4*)&swf[sr * 68 + dl];
      const int s = m0 + wm * 32 + mt * 16 + sr;
      *(float4*)(out + (size_t)s * 512 + n0 + wn * 64 + dl) = v;
    }
  }
}

// ---------------- launch --------------------------------------------------
extern "C" void kernel_launch(void* const* d_in, const int* in_sizes, int n_in,
                              void* d_out, int out_size, void* d_ws, size_t ws_size,
                              hipStream_t stream) {
  const float* x       = (const float*)d_in[0];
  const float* wq      = (const float*)d_in[1];
  const float* wk      = (const float*)d_in[2];
  const float* wv      = (const float*)d_in[3];
  const float* wo      = (const float*)d_in[4];
  const float* rel_row = (const float*)d_in[5];
  const float* rel_col = (const float*)d_in[6];
  float* out = (float*)d_out;

  char* ws = (char*)d_ws;
  u16* wT    = (u16*)(ws);                               // 3 * 512*512 bf16
  u16* woT   = (u16*)(ws + 1572864);                     // 512*512 bf16
  u16* qbuf  = (u16*)(ws + 2097152);                     // 16 MiB
  u16* kbuf  = (u16*)(ws + 2097152 + 16777216);          // 16 MiB
  u16* vtbuf = (u16*)(ws + 2097152 + 2 * 16777216);      // 16 MiB
  u16* obuf  = (u16*)(ws + 2097152 + 3 * 16777216);      // 16 MiB
  float* opart = (float*)(ws + 2097152 + 4 * 16777216);  // 32 MiB (2 slots)
  float* lpart = (float*)(ws + 2097152 + 6 * 16777216);  // 256 KiB (2 slots)
  u16* xb    = obuf;  // xb consumed by qkv_gemm before attn writes obuf

  xcast_tr<<<4352, 256, 0, stream>>>(x, xb, wq, wk, wv, wo, wT, woT);
  qkv_gemm<<<dim3(128, 12), 512, 0, stream>>>(xb, wT, qbuf, kbuf, vtbuf);
  attn<<<1024, 128, 0, stream>>>(qbuf, kbuf, vtbuf, rel_row, rel_col, obuf, opart, lpart);
  onorm<<<2048, 256, 0, stream>>>(opart, lpart, obuf);
  out_gemm<<<dim3(128, 4), 512, 0, stream>>>(obuf, woT, out);
}

// Round 14
// 241.988 us; speedup vs baseline: 1.5721x; 1.0618x over previous
//
#include <hip/hip_runtime.h>
#include <cstdint>

typedef unsigned short u16;
typedef __attribute__((ext_vector_type(8))) short short8;
typedef __attribute__((ext_vector_type(4))) short short4v;
typedef __attribute__((ext_vector_type(4))) float f32x4;
typedef __attribute__((ext_vector_type(4))) unsigned short u16x4;
typedef __attribute__((ext_vector_type(2))) float f32x2;
typedef __attribute__((ext_vector_type(2))) __bf16 bf16x2;

// B=4 R=64 C=64 D=512 H=4 DH=128 S=4096, M = B*S = 16384

#if defined(__has_builtin)
#if __has_builtin(__builtin_amdgcn_mfma_f32_16x16x16bf16_1k)
#define HAVE_MFMA16 1
#endif
#endif

// HW packed f32->bf16 (RNE): single v_cvt_pk_bf16_f32.
__device__ __forceinline__ uint32_t pk2(float a, float b) {
  f32x2 t;
  t[0] = a;
  t[1] = b;
  bf16x2 h = __builtin_convertvector(t, bf16x2);
  return __builtin_bit_cast(uint32_t, h);
}

__device__ __forceinline__ u16 f2b(float f) {
  return __builtin_bit_cast(u16, (__bf16)f);
}

// RNE f32x4 (scaled) -> 4 packed bf16 (2x v_cvt_pk_bf16_f32)
__device__ __forceinline__ uint2 pkbf16x4(f32x4 v, float s) {
  uint2 r;
  r.x = pk2(v[0] * s, v[1] * s);
  r.y = pk2(v[2] * s, v[3] * s);
  return r;
}

// async global->LDS, 16B per lane. LDS dest = wave-uniform base + lane*16.
__device__ __forceinline__ void dma16(const u16* g, u16* l) {
  __builtin_amdgcn_global_load_lds(
      (const __attribute__((address_space(1))) unsigned int*)(uintptr_t)g,
      (__attribute__((address_space(3))) unsigned int*)(uintptr_t)l, 16, 0, 0);
}

#define LDS_FENCE() asm volatile("s_waitcnt lgkmcnt(0)" ::: "memory")

// ---------------- fused: x fp32->bf16 cast + weight transposes -----------
// blocks [0,4096): xcast. blocks [4096,4352): transpose (64 tiles x 4 mtx).
__global__ __launch_bounds__(256) void xcast_tr(const float* __restrict__ x,
                                                u16* __restrict__ xb,
                                                const float* __restrict__ wq,
                                                const float* __restrict__ wk,
                                                const float* __restrict__ wv,
                                                const float* __restrict__ wo,
                                                u16* __restrict__ wT,
                                                u16* __restrict__ woT) {
  __shared__ __align__(16) u16 T[64][68];
  const int tid = threadIdx.x;
  if (blockIdx.x < 4096) {
    const size_t i = (size_t)(blockIdx.x * 256 + tid) * 8;
    const float4 a = *(const float4*)(x + i);
    const float4 b = *(const float4*)(x + i + 4);
    uint4 o;
    o.x = pk2(a.x, a.y);
    o.y = pk2(a.z, a.w);
    o.z = pk2(b.x, b.y);
    o.w = pk2(b.z, b.w);
    *(uint4*)(xb + i) = o;
    return;
  }
  const int bid2 = blockIdx.x - 4096;
  const int mtx = bid2 >> 6, t = bid2 & 63;
  const float* src = (mtx == 0) ? wq : (mtx == 1) ? wk : (mtx == 2) ? wv : wo;
  u16* dst = (mtx < 3) ? (wT + (size_t)mtx * 262144) : woT;
  const int tr = t >> 3, tc = t & 7;
#pragma unroll
  for (int p = 0; p < 4; ++p) {
    int i = p * 256 + tid;
    int row = i >> 4, c4 = i & 15;
    float4 v = *(const float4*)(src + (size_t)(tr * 64 + row) * 512 + tc * 64 + c4 * 4);
    T[c4 * 4 + 0][row] = f2b(v.x);
    T[c4 * 4 + 1][row] = f2b(v.y);
    T[c4 * 4 + 2][row] = f2b(v.z);
    T[c4 * 4 + 3][row] = f2b(v.w);
  }
  __syncthreads();
#pragma unroll
  for (int p = 0; p < 4; ++p) {
    int i = p * 256 + tid;
    int row = i >> 4, c4 = i & 15;
    *(u16x4*)(dst + (size_t)(tc * 64 + row) * 512 + tr * 64 + c4 * 4) =
        *(const u16x4*)&T[row][c4 * 4];
  }
}

// ---------------- QKV projection GEMM ------------------------------------
// R11-exact. N=128 units, grid 128x12 = 1536 blocks = 3 rounds at 2
// blocks/CU. 8 waves as 4m x 2n, acc[2][4]. dma16 staging, XOR chunk
// swizzle. (512,4): R12 proved (512,6) forces 40-VGPR spill catastrophe.
__global__ __launch_bounds__(512, 4) void qkv_gemm(const u16* __restrict__ xb,
                                                   const u16* __restrict__ wT_all,
                                                   u16* __restrict__ qbuf,
                                                   u16* __restrict__ kbuf,
                                                   u16* __restrict__ vtbuf) {
  __shared__ __align__(16) u16 smem[18432];  // staging 32 KB; epilogue 36 KB
  u16* As = smem;              // [128][64] swizzled (s rows)
  u16* Bs = smem + 128 * 64;   // [128][64] swizzled (dh rows)
  const int tid = threadIdx.x;
  const int wave = tid >> 6, lane = tid & 63, quad = lane >> 4, l16 = lane & 15;
  const int wm = wave >> 1, wn = wave & 1;
  const int ldrow = lane >> 3;        // 0..7 (== row&7 of the staged row)
  const int ldcs = ((lane & 7) ^ ldrow) * 8;   // pre-swizzled global chunk
  const int m0 = blockIdx.x * 128;
  const int which = blockIdx.y >> 2;            // 0=q 1=k 2=v
  const int n0 = (blockIdx.y & 3) * 128;        // dh offset within which
  const u16* wTb = wT_all + (size_t)which * 262144 + (size_t)n0 * 512;

  f32x4 acc[2][4];
  const f32x4 fz = {0.f, 0.f, 0.f, 0.f};
#pragma unroll
  for (int i = 0; i < 2; ++i)
#pragma unroll
    for (int j = 0; j < 4; ++j) acc[i][j] = fz;

  for (int k0 = 0; k0 < 512; k0 += 64) {
#pragma unroll
    for (int p = 0; p < 2; ++p) {
      const int row = (p * 8 + wave) * 8 + ldrow;
      dma16(xb + (size_t)(m0 + row) * 512 + k0 + ldcs, As + (p * 8 + wave) * 512);
    }
#pragma unroll
    for (int p = 0; p < 2; ++p) {
      const int row = (p * 8 + wave) * 8 + ldrow;
      dma16(wTb + (size_t)row * 512 + k0 + ldcs, Bs + (p * 8 + wave) * 512);
    }
    __syncthreads();   // drains vmcnt -> chunk resident
#pragma unroll
    for (int ks = 0; ks < 2; ++ks) {
      short8 xf[2], wf[4];
#pragma unroll
      for (int mt = 0; mt < 2; ++mt)
        xf[mt] = *(const short8*)&As[(wm * 32 + mt * 16 + l16) * 64 +
                                     ((ks * 32 + quad * 8) ^ ((l16 & 7) * 8))];
#pragma unroll
      for (int nt = 0; nt < 4; ++nt)
        wf[nt] = *(const short8*)&Bs[(wn * 64 + nt * 16 + l16) * 64 +
                                     ((ks * 32 + quad * 8) ^ ((l16 & 7) * 8))];
      if (which < 2) {
#pragma unroll
        for (int mt = 0; mt < 2; ++mt)
#pragma unroll
          for (int nt = 0; nt < 4; ++nt)
            acc[mt][nt] = __builtin_amdgcn_mfma_f32_16x16x32_bf16(wf[nt], xf[mt],
                                                                  acc[mt][nt], 0, 0, 0);
      } else {
#pragma unroll
        for (int mt = 0; mt < 2; ++mt)
#pragma unroll
          for (int nt = 0; nt < 4; ++nt)
            acc[mt][nt] = __builtin_amdgcn_mfma_f32_16x16x32_bf16(xf[mt], wf[nt],
                                                                  acc[mt][nt], 0, 0, 0);
      }
    }
    __syncthreads();   // readers done before next chunk overwrites
  }
  // Per-wave private smem slice (2304 u16).
  u16* sw = smem + wave * 2304;
  const int dhg0 = n0 + wn * 64;
  const int h = dhg0 >> 7, dhh0 = dhg0 & 127;
  const int bq = m0 >> 12;
  const int bh = bq * 4 + h;
  const int sl0 = (m0 & 4095) + wm * 32;

  if (which < 2) {
    const float scl = (which == 0) ? 0.08838834764831845f : 1.0f;  // DH^-0.5 on q
    u16* dst = (which == 0) ? qbuf : kbuf;
#pragma unroll
    for (int mt = 0; mt < 2; ++mt) {
      LDS_FENCE();  // prior readback done before overwrite
#pragma unroll
      for (int nt = 0; nt < 4; ++nt)
        *(uint2*)&sw[l16 * 68 + nt * 16 + quad * 4] = pkbf16x4(acc[mt][nt], scl);
      LDS_FENCE();
#pragma unroll
      for (int p = 0; p < 2; ++p) {
        const int sr = p * 8 + (lane >> 3), dl = (lane & 7) * 8;
        uint4 v = *(const uint4*)&sw[sr * 68 + dl];
        const int sl = sl0 + mt * 16 + sr;
        *(uint4*)(dst + ((size_t)(bh * 4096 + sl)) * 128 + dhh0 + dl) = v;
      }
    }
  } else {
    // v: scratch [64 dh][32 s + pad4], single pass (wave owns 32 s)
    LDS_FENCE();
#pragma unroll
    for (int mt = 0; mt < 2; ++mt)
#pragma unroll
      for (int nt = 0; nt < 4; ++nt)
        *(uint2*)&sw[(nt * 16 + l16) * 36 + mt * 16 + quad * 4] =
            pkbf16x4(acc[mt][nt], 1.0f);
    LDS_FENCE();
#pragma unroll
    for (int j = 0; j < 4; ++j) {
      const int dl = j * 16 + (lane >> 2), so = (lane & 3) * 8;
      uint4 v = *(const uint4*)&sw[dl * 36 + so];
      const int sl = sl0 + so;
      *(uint4*)(vtbuf + ((size_t)(bh * 128 + dhh0 + dl)) * 4096 + sl) = v;
    }
  }
}

// ---------------- causal flash attention, balanced split-K jobs ----------
// R11-exact attn (best measured: 117.1-119.2 us). 1024 blocks x 128
// threads (2 waves), equal-cost jobs (~32.5 key-tiles each). Max-free
// softmax -> linear partial combine in onorm. 32q/wave (g=0,1) K/V
// fragment sharing, dma16 staging, XOR-swizzled LDS, K=16 PV from QK^T
// C-fragments. 33.8 KB LDS -> 4 blocks/CU. Per-element diag cndmask kept
// in the single softmax path: R13 proved the branch-split version spills
// (FETCH 38->138 MB, attn +13 us) despite identical VGPR_Count.
__global__ __launch_bounds__(128, 2) void attn(const u16* __restrict__ qbuf,
                                               const u16* __restrict__ kbuf,
                                               const u16* __restrict__ vtbuf,
                                               const float* __restrict__ rel_row,
                                               const float* __restrict__ rel_col,
                                               u16* __restrict__ obuf,
                                               float* __restrict__ opart,
                                               float* __restrict__ lpart) {
  __shared__ __align__(16) u16 KsF[64 * 128];   // [key][dh], col ^= (row&7)*8
  __shared__ __align__(16) u16 VtF[128 * 64];   // [dh][key], col ^= (row&7)*8
#ifndef HAVE_MFMA16
  __shared__ __align__(16) u16 Plds[2][2][16][72];
#endif
  __shared__ float rcol[128];
  __shared__ float rrow[128];

  const int tid = threadIdx.x;
  const int wave = tid >> 6, lane = tid & 63, quad = lane >> 4, l16 = lane & 15;
  const int jid = blockIdx.x;
  const int bh = jid & 15, p = (jid >> 4) & 31, half = jid >> 9;
  const int b = bh >> 2, h = bh & 3;

  const float LOG2E = 1.4426950408889634f;
  rcol[tid] = rel_col[h * 128 + tid] * LOG2E;
  rrow[tid] = rel_row[h * 128 + tid] * LOG2E;

  const int q0 = wave * 32 + l16;           // g adds +16

  __syncthreads();   // rcol/rrow visible

  float rc2[2][4][4];
#pragma unroll
  for (int g = 0; g < 2; ++g)
#pragma unroll
    for (int nt = 0; nt < 4; ++nt)
#pragma unroll
      for (int r = 0; r < 4; ++r)
        rc2[g][nt][r] = rcol[63 + nt * 16 + quad * 4 + r - (q0 + g * 16)];

  const f32x4 fz = {0.f, 0.f, 0.f, 0.f};
  const u16* kbase = kbuf + (size_t)bh * 4096 * 128;
  const u16* vbase = vtbuf + (size_t)bh * 128 * 4096;
  // staging coords (8 rounds K + 8 rounds V per tile, 1 KB/round/wave);
  // global col pre-swizzled so the linear LDS fill lands swizzled rows.
  const int krow = wave * 4 + (lane >> 4);            // 0..7
  const int kcs = ((lane & 15) ^ krow) * 8;
  const int vrow = wave * 8 + (lane >> 3);            // 0..15
  const int vcs = ((lane & 7) ^ (vrow & 7)) * 8;

  auto run_row = [&](int r, int ktb, int kte, bool direct) {
    const u16* qrow0 = qbuf + ((size_t)bh * 4096 + r * 64 + q0) * 128;
    short8 qf[2][4];
#pragma unroll
    for (int g = 0; g < 2; ++g)
#pragma unroll
      for (int ks = 0; ks < 4; ++ks)
        qf[g][ks] = *(const short8*)(qrow0 + (size_t)g * 16 * 128 + ks * 32 + quad * 8);
    f32x4 oacc[2][8];
#pragma unroll
    for (int g = 0; g < 2; ++g)
#pragma unroll
      for (int i = 0; i < 8; ++i) oacc[g][i] = fz;
    float l_run[2] = {0.0f, 0.0f};

    for (int kt = ktb; kt < kte; ++kt) {
      __syncthreads();   // all waves done reading previous tile
      {
        const u16* ksrc = kbase + (size_t)kt * 8192;
        const u16* vsrc = vbase + (size_t)kt * 64;
        u16* kd = KsF + wave * 512;
        u16* vd = VtF + wave * 512;
#pragma unroll
        for (int j = 0; j < 8; ++j)
          dma16(ksrc + (size_t)(j * 8 + krow) * 128 + kcs, kd + j * 1024);
#pragma unroll
        for (int j = 0; j < 8; ++j)
          dma16(vsrc + (size_t)(j * 16 + vrow) * 4096 + vcs, vd + j * 1024);
      }
      __syncthreads();   // drains vmcnt -> tile resident

      // Sᵀ tiles: rows = key (nt), cols = q (l16); each kf feeds both g.
      f32x4 sacc[2][4];
#pragma unroll
      for (int g = 0; g < 2; ++g)
#pragma unroll
        for (int nt = 0; nt < 4; ++nt) sacc[g][nt] = fz;
      __builtin_amdgcn_s_setprio(1);
#pragma unroll
      for (int ks = 0; ks < 4; ++ks)
#pragma unroll
        for (int nt = 0; nt < 4; ++nt) {
          short8 kf = *(const short8*)&KsF[(nt * 16 + l16) * 128 +
                                           ((ks * 32 + quad * 8) ^ ((l16 & 7) * 8))];
          sacc[0][nt] = __builtin_amdgcn_mfma_f32_16x16x32_bf16(kf, qf[0][ks], sacc[0][nt], 0, 0, 0);
          sacc[1][nt] = __builtin_amdgcn_mfma_f32_16x16x32_bf16(kf, qf[1][ks], sacc[1][nt], 0, 0, 0);
        }
      __builtin_amdgcn_s_setprio(0);

      const float browl = rrow[63 + kt - r];
      const bool diag = (kt == r);
      uint2 pd[2][4];
#pragma unroll
      for (int g = 0; g < 2; ++g) {
        const int qc = q0 + g * 16;
#pragma unroll
        for (int nt = 0; nt < 4; ++nt) {
          f32x4 pv;
#pragma unroll
          for (int rr = 0; rr < 4; ++rr) {
            const int kc2 = nt * 16 + quad * 4 + rr;
            float pe = __builtin_amdgcn_exp2f(fmaf(sacc[g][nt][rr], LOG2E, rc2[g][nt][rr] + browl));
            if (diag && kc2 > qc) pe = 0.0f;
            l_run[g] += pe;
            pv[rr] = pe;
          }
          pd[g][nt].x = pk2(pv[0], pv[1]);
          pd[g][nt].y = pk2(pv[2], pv[3]);
        }
      }

#ifdef HAVE_MFMA16
      // Oᵀ += Vᵀ·Pᵀ with K=16 MFMA; each vf feeds both g.
      __builtin_amdgcn_s_setprio(1);
#pragma unroll
      for (int nt = 0; nt < 4; ++nt) {
        short4v pf0 = __builtin_bit_cast(short4v, pd[0][nt]);
        short4v pf1 = __builtin_bit_cast(short4v, pd[1][nt]);
#pragma unroll
        for (int mt = 0; mt < 8; ++mt) {
          short4v vf = *(const short4v*)&VtF[(mt * 16 + l16) * 64 +
                                             ((nt * 16 + quad * 4) ^ ((l16 & 7) * 8))];
          oacc[0][mt] = __builtin_amdgcn_mfma_f32_16x16x16bf16_1k(vf, pf0, oacc[0][mt], 0, 0, 0);
          oacc[1][mt] = __builtin_amdgcn_mfma_f32_16x16x16bf16_1k(vf, pf1, oacc[1][mt], 0, 0, 0);
        }
      }
      __builtin_amdgcn_s_setprio(0);
#else
#pragma unroll
      for (int g = 0; g < 2; ++g)
#pragma unroll
        for (int nt = 0; nt < 4; ++nt)
          *(uint2*)&Plds[wave][g][l16][nt * 16 + quad * 4] = pd[g][nt];
#pragma unroll
      for (int g = 0; g < 2; ++g)
#pragma unroll
        for (int ks2 = 0; ks2 < 2; ++ks2) {
          short8 pf = *(const short8*)&Plds[wave][g][l16][ks2 * 32 + quad * 8];
#pragma unroll
          for (int mt = 0; mt < 8; ++mt) {
            short8 vf = *(const short8*)&VtF[(mt * 16 + l16) * 64 +
                                             ((ks2 * 32 + quad * 8) ^ ((l16 & 7) * 8))];
            oacc[g][mt] = __builtin_amdgcn_mfma_f32_16x16x32_bf16(vf, pf, oacc[g][mt], 0, 0, 0);
          }
        }
#endif
    }

#pragma unroll
    for (int g = 0; g < 2; ++g) {
      l_run[g] += __shfl_xor(l_run[g], 16);
      l_run[g] += __shfl_xor(l_run[g], 32);
    }
    if (direct) {
#pragma unroll
      for (int g = 0; g < 2; ++g) {
        const float inv_l = 1.0f / l_run[g];
        u16* orow = obuf + ((size_t)b * 4096 + r * 64 + q0 + g * 16) * 512 + h * 128;
#pragma unroll
        for (int mt = 0; mt < 8; ++mt)
          *(uint2*)(orow + mt * 16 + quad * 4) = pkbf16x4(oacc[g][mt], inv_l);
      }
    } else {
#pragma unroll
      for (int g = 0; g < 2; ++g) {
        const size_t qi = (size_t)((half * 16 + bh) * 32 + (r - 32)) * 64 + q0 + g * 16;
        float* od = opart + qi * 128;
#pragma unroll
        for (int mt = 0; mt < 8; ++mt)
          *(f32x4*)(od + mt * 16 + quad * 4) = oacc[g][mt];
        if (quad == 0) lpart[qi] = l_run[g];
      }
    }
  };

  if (half == 0) {
    run_row(p, 0, p + 1, true);          // row A complete (incl. diagonal)
    run_row(63 - p, 0, 32 - p, false);   // row B lower partial
  } else {
    run_row(63 - p, 32 - p, 64 - p, false);  // row B upper partial (incl. diag)
  }
}

// ---------------- combine row-B partials + normalize ---------------------
__global__ __launch_bounds__(256) void onorm(const float* __restrict__ opart,
                                             const float* __restrict__ lpart,
                                             u16* __restrict__ obuf) {
  const int gi = blockIdx.x * 256 + threadIdx.x;   // 524288 total
  const int d8 = (gi & 15) * 8;
  const int qi = gi >> 4;                          // (bh*32+rr)*64+q
  const int q = qi & 63, rr = (qi >> 6) & 31, bh = qi >> 11;
  const float inv = 1.0f / (lpart[qi] + lpart[32768 + qi]);
  const float* s0 = opart + (size_t)qi * 128 + d8;
  const float* s1 = s0 + 4194304;                  // second half slot
  f32x4 a0 = *(const f32x4*)s0;
  f32x4 b0 = *(const f32x4*)(s0 + 4);
  f32x4 a1 = *(const f32x4*)s1;
  f32x4 b1 = *(const f32x4*)(s1 + 4);
  f32x4 sa = a0 + a1, sb = b0 + b1;
  uint4 o;
  o.x = pk2(sa[0] * inv, sa[1] * inv);
  o.y = pk2(sa[2] * inv, sa[3] * inv);
  o.z = pk2(sb[0] * inv, sb[1] * inv);
  o.w = pk2(sb[2] * inv, sb[3] * inv);
  const int b = bh >> 2, h = bh & 3;
  const int q_glob = (32 + rr) * 64 + q;
  *(uint4*)(obuf + ((size_t)b * 4096 + q_glob) * 512 + h * 128 + d8) = o;
}

// ---------------- output projection GEMM ---------------------------------
// N=128 -> grid 128x4 = 512 blocks = exact 2-blocks/CU fill. 8 waves as
// 4m x 2n, acc[2][4]. dma16 staging, same swizzle.
__global__ __launch_bounds__(512, 4) void out_gemm(const u16* __restrict__ obuf,
                                                   const u16* __restrict__ woT,
                                                   float* __restrict__ out) {
  __shared__ __align__(16) u16 smem[18432];  // staging 32 KB; f32 epilogue 36 KB
  u16* As = smem;              // [128][64] obuf rows (s), swizzled
  u16* Bs = smem + 128 * 64;   // [128][64] woT rows (d), swizzled
  const int tid = threadIdx.x;
  const int wave = tid >> 6, lane = tid & 63, quad = lane >> 4, l16 = lane & 15;
  const int wm = wave >> 1, wn = wave & 1;
  const int ldrow = lane >> 3;
  const int ldcs = ((lane & 7) ^ ldrow) * 8;
  const int m0 = blockIdx.x * 128;
  const int n0 = blockIdx.y * 128;

  f32x4 acc[2][4];
  const f32x4 fz = {0.f, 0.f, 0.f, 0.f};
#pragma unroll
  for (int i = 0; i < 2; ++i)
#pragma unroll
    for (int j = 0; j < 4; ++j) acc[i][j] = fz;

  for (int k0 = 0; k0 < 512; k0 += 64) {
#pragma unroll
    for (int p = 0; p < 2; ++p) {
      const int row = (p * 8 + wave) * 8 + ldrow;
      dma16(obuf + (size_t)(m0 + row) * 512 + k0 + ldcs, As + (p * 8 + wave) * 512);
    }
#pragma unroll
    for (int p = 0; p < 2; ++p) {
      const int row = (p * 8 + wave) * 8 + ldrow;
      dma16(woT + (size_t)(n0 + row) * 512 + k0 + ldcs, Bs + (p * 8 + wave) * 512);
    }
    __syncthreads();
#pragma unroll
    for (int ks = 0; ks < 2; ++ks) {
      short8 of[2], wf[4];
#pragma unroll
      for (int mt = 0; mt < 2; ++mt)
        of[mt] = *(const short8*)&As[(wm * 32 + mt * 16 + l16) * 64 +
                                     ((ks * 32 + quad * 8) ^ ((l16 & 7) * 8))];
#pragma unroll
      for (int nt = 0; nt < 4; ++nt)
        wf[nt] = *(const short8*)&Bs[(wn * 64 + nt * 16 + l16) * 64 +
                                     ((ks * 32 + quad * 8) ^ ((l16 & 7) * 8))];
#pragma unroll
      for (int mt = 0; mt < 2; ++mt)
#pragma unroll
        for (int nt = 0; nt < 4; ++nt)
          acc[mt][nt] = __builtin_amdgcn_mfma_f32_16x16x32_bf16(wf[nt], of[mt],
                                                                acc[mt][nt], 0, 0, 0);
    }
    __syncthreads();
  }

  float* swf = (float*)smem + wave * 1152;   // per-wave [16 s][68 d] f32
#pragma unroll
  for (int mt = 0; mt < 2; ++mt) {
    LDS_FENCE();
#pragma unroll
    for (int nt = 0; nt < 4; ++nt)
      *(f32x4*)&swf[l16 * 68 + nt * 16 + quad * 4] = acc[mt][nt];
    LDS_FENCE();
#pragma unroll
    for (int p = 0; p < 4; ++p) {
      const int sr = p * 4 + (lane >> 4), dl = l16 * 4;
      float4 v = *(const float4*)&swf[sr * 68 + dl];
      const int s = m0 + wm * 32 + mt * 16 + sr;
      *(float4*)(out + (size_t)s * 512 + n0 + wn * 64 + dl) = v;
    }
  }
}

// ---------------- launch --------------------------------------------------
extern "C" void kernel_launch(void* const* d_in, const int* in_sizes, int n_in,
                              void* d_out, int out_size, void* d_ws, size_t ws_size,
                              hipStream_t stream) {
  const float* x       = (const float*)d_in[0];
  const float* wq      = (const float*)d_in[1];
  const float* wk      = (const float*)d_in[2];
  const float* wv      = (const float*)d_in[3];
  const float* wo      = (const float*)d_in[4];
  const float* rel_row = (const float*)d_in[5];
  const float* rel_col = (const float*)d_in[6];
  float* out = (float*)d_out;

  char* ws = (char*)d_ws;
  u16* wT    = (u16*)(ws);                               // 3 * 512*512 bf16
  u16* woT   = (u16*)(ws + 1572864);                     // 512*512 bf16
  u16* qbuf  = (u16*)(ws + 2097152);                     // 16 MiB
  u16* kbuf  = (u16*)(ws + 2097152 + 16777216);          // 16 MiB
  u16* vtbuf = (u16*)(ws + 2097152 + 2 * 16777216);      // 16 MiB
  u16* obuf  = (u16*)(ws + 2097152 + 3 * 16777216);      // 16 MiB
  float* opart = (float*)(ws + 2097152 + 4 * 16777216);  // 32 MiB (2 slots)
  float* lpart = (float*)(ws + 2097152 + 6 * 16777216);  // 256 KiB (2 slots)
  u16* xb    = obuf;  // xb consumed by qkv_gemm before attn writes obuf

  xcast_tr<<<4352, 256, 0, stream>>>(x, xb, wq, wk, wv, wo, wT, woT);
  qkv_gemm<<<dim3(128, 12), 512, 0, stream>>>(xb, wT, qbuf, kbuf, vtbuf);
  attn<<<1024, 128, 0, stream>>>(qbuf, kbuf, vtbuf, rel_row, rel_col, obuf, opart, lpart);
  onorm<<<2048, 256, 0, stream>>>(opart, lpart, obuf);
  out_gemm<<<dim3(128, 4), 512, 0, stream>>>(obuf, woT, out);
}